// Round 3
// baseline (163.954 us; speedup 1.0000x reference)
//
#include <hip/hip_runtime.h>
#include <math.h>

// Problem constants: B=32, F=2048, hw=49, A=1.
#define BB    32
#define FF    2048
#define HW    49
#define ROWS  (BB * FF)
#define DPAD  64
#define SPLIT 4
#define GSTEP 32
#define FBLK  128
#define GHALF (FF / SPLIT)              // 512
#define NSTEP (GHALF / GSTEP)           // 16

typedef float f32x16 __attribute__((ext_vector_type(16)));
typedef short bf16x8 __attribute__((ext_vector_type(8)));

// fp32 -> bf16 hi + bf16 lo (both RNE), packed (hi<<16)|lo.
__device__ inline unsigned bf16pack(float v) {
    unsigned u = __float_as_uint(v);
    unsigned hi = (u + 0x7FFFu + ((u >> 16) & 1u)) >> 16;
    float hf = __uint_as_float(hi << 16);
    float lof = v - hf;
    unsigned ul = __float_as_uint(lof);
    unsigned lo = (ul + 0x7FFFu + ((ul >> 16) & 1u)) >> 16;
    return (hi << 16) | lo;
}

// ---------------------------------------------------------------------------
// prep: M[j,d] = sum_e Wq[e,j] Wk[e,d] / 7  -> Mt (transposed, hi/lo packed)
//       u[d]   = sum_e Wv[e,d] * Wout[e]
// Blocks 0..15: 4 Mt rows each. Block 16: u.
// ---------------------------------------------------------------------------
__global__ __launch_bounds__(256) void prep_kernel(
    const float* __restrict__ Wqkv, const float* __restrict__ Wout,
    unsigned* __restrict__ Mtpk, float* __restrict__ u)
{
    __shared__ float W2[98][52];
    const int tid = threadIdx.x;
    if (blockIdx.x < 16) {
        for (int i = tid; i < 98 * 52; i += 256) {
            int e = i / 52, j = i - e * 52;
            W2[e][j] = (j < HW) ? Wqkv[e * HW + j] : 0.f;
        }
        __syncthreads();
        const int d = blockIdx.x * 4 + (tid >> 6);
        const int j = tid & 63;
        float s = 0.f;
        if (d < HW && j < HW) {
            for (int e = 0; e < HW; ++e) s = fmaf(W2[e][j], W2[49 + e][d], s);
            s *= (1.f / 7.f);
        }
        Mtpk[d * 64 + j] = bf16pack(s);
    } else {
        if (tid < 64) {
            float s = 0.f;
            if (tid < HW)
                for (int e = 0; e < HW; ++e)
                    s = fmaf(Wqkv[(98 + e) * HW + tid], Wout[e], s);
            u[tid] = s;
        }
    }
}

// ---------------------------------------------------------------------------
// xconv: x fp32 [row][49] -> xh/xl bf16 panels [row][64] (zero-padded),
//        w[row] = x . u.   4 threads per row for coalesced 32B stores.
// ---------------------------------------------------------------------------
__global__ __launch_bounds__(256) void xconv_kernel(
    const float* __restrict__ x, const float* __restrict__ u,
    unsigned short* __restrict__ xh, unsigned short* __restrict__ xl,
    float* __restrict__ wv)
{
    __shared__ float ush[64];
    const int tid = threadIdx.x;
    if (tid < 64) ush[tid] = u[tid];
    __syncthreads();

    const int row = blockIdx.x * 64 + (tid >> 2);
    const int q4 = tid & 3, d0 = q4 * 16;
    const float* xp = x + (size_t)row * HW;

    float v[16];
    float wp = 0.f;
    #pragma unroll
    for (int i = 0; i < 16; ++i) {
        int d = d0 + i;
        float t = (d < HW) ? xp[d] : 0.f;
        v[i] = t;
        wp = fmaf(t, ush[d], wp);
    }
    wp += __shfl_xor(wp, 1);
    wp += __shfl_xor(wp, 2);
    if (q4 == 0) wv[row] = wp;

    unsigned ph[8], pl[8];
    #pragma unroll
    for (int i = 0; i < 8; ++i) {
        unsigned p0 = bf16pack(v[2 * i]);
        unsigned p1 = bf16pack(v[2 * i + 1]);
        ph[i] = (p0 >> 16) | (p1 & 0xFFFF0000u);
        pl[i] = (p0 & 0xFFFFu) | (p1 << 16);
    }
    const size_t o = (size_t)row * DPAD + d0;
    *(uint4*)(xh + o)     = make_uint4(ph[0], ph[1], ph[2], ph[3]);
    *(uint4*)(xh + o + 8) = make_uint4(ph[4], ph[5], ph[6], ph[7]);
    *(uint4*)(xl + o)     = make_uint4(pl[0], pl[1], pl[2], pl[3]);
    *(uint4*)(xl + o + 8) = make_uint4(pl[4], pl[5], pl[6], pl[7]);
}

__device__ inline void unpack8(uint4 a, uint4 b, bf16x8& h, bf16x8& l) {
    unsigned w[8] = {a.x, a.y, a.z, a.w, b.x, b.y, b.z, b.w};
    #pragma unroll
    for (int i = 0; i < 8; ++i) {
        h[i] = (short)(w[i] >> 16);
        l[i] = (short)(w[i] & 0xFFFFu);
    }
}

// ---------------------------------------------------------------------------
// ymm: y = x . M  (3-MFMA hi/lo), output packed u32 panel ypk[row][64].
// Block: 4 waves x 32 rows. Mt fragments hoisted in registers.
// ---------------------------------------------------------------------------
__global__ __launch_bounds__(256) void ymm_kernel(
    const unsigned short* __restrict__ xh, const unsigned short* __restrict__ xl,
    const unsigned* __restrict__ Mtpk, unsigned* __restrict__ ypk)
{
    const int tid = threadIdx.x, lane = tid & 63, wid = tid >> 6;
    const int col = lane & 31, half = lane >> 5;
    const int r0 = blockIdx.x * 128 + wid * 32;

    bf16x8 mh[2][4], ml[2][4];
    #pragma unroll
    for (int dt = 0; dt < 2; ++dt)
        #pragma unroll
        for (int ks = 0; ks < 4; ++ks) {
            const unsigned* mp = Mtpk + (dt * 32 + col) * 64 + ks * 16 + half * 8;
            unpack8(*(const uint4*)mp, *(const uint4*)(mp + 4), mh[dt][ks], ml[dt][ks]);
        }

    f32x16 acc[2];
    #pragma unroll
    for (int i = 0; i < 16; ++i) { acc[0][i] = 0.f; acc[1][i] = 0.f; }

    const size_t rowb = (size_t)(r0 + col) * DPAD;
    #pragma unroll
    for (int ks = 0; ks < 4; ++ks) {
        bf16x8 ah = *(const bf16x8*)(xh + rowb + ks * 16 + half * 8);
        bf16x8 al = *(const bf16x8*)(xl + rowb + ks * 16 + half * 8);
        #pragma unroll
        for (int dt = 0; dt < 2; ++dt) {
            acc[dt] = __builtin_amdgcn_mfma_f32_32x32x16_bf16(ah, ml[dt][ks], acc[dt], 0, 0, 0);
            acc[dt] = __builtin_amdgcn_mfma_f32_32x32x16_bf16(al, mh[dt][ks], acc[dt], 0, 0, 0);
            acc[dt] = __builtin_amdgcn_mfma_f32_32x32x16_bf16(ah, mh[dt][ks], acc[dt], 0, 0, 0);
        }
    }

    #pragma unroll
    for (int dt = 0; dt < 2; ++dt)
        #pragma unroll
        for (int reg = 0; reg < 16; ++reg) {
            int drow = (reg & 3) + 8 * (reg >> 2) + 4 * half;
            ypk[(size_t)(r0 + drow) * DPAD + dt * 32 + col] = bf16pack(acc[dt][reg]);
        }
}

// ---------------------------------------------------------------------------
// attn: scores = y . x^T (3-MFMA hi/lo), no-max softmax with scalar value w.
// A-side = x panels staged via swizzled LDS dbuf; B-side = y frags hoisted.
// w staged to LDS once per block. 8 blocks/CU.
// ---------------------------------------------------------------------------
__global__ __launch_bounds__(256, 8) void attn_kernel(
    const unsigned short* __restrict__ xh, const unsigned short* __restrict__ xl,
    const unsigned* __restrict__ ypk, const float* __restrict__ wv,
    float* __restrict__ partL, float* __restrict__ partA)
{
    __shared__ __align__(16) unsigned char Kt[2][8192];
    __shared__ __align__(16) float wssh[GHALF];

    // XCD-chunked swizzle: 2048 blocks, 256 consecutive logical ids per XCD
    // -> each XCD holds 4 consecutive b (x/y panels L2-resident).
    const int bid = blockIdx.x;
    const int L = (bid & 7) * 256 + (bid >> 3);
    const int b  = L >> 6;
    const int rr = L & 63;
    const int ft = rr >> 2;         // 0..15
    const int sp = rr & 3;          // 0..3

    const int tid  = threadIdx.x;
    const int lane = tid & 63;
    const int wid  = tid >> 6;
    const int col  = lane & 31;
    const int half = lane >> 5;
    const int fbase  = ft * FBLK + wid * 32;
    const int gstart = sp * GHALF;
    const size_t bq = (size_t)b * FF;

    // hoist y fragments (B operand, col = fbase+col), unpack hi/lo
    bf16x8 qhf[4], qlf[4];
    {
        const size_t yrow = (bq + fbase + col) * DPAD;
        #pragma unroll
        for (int ks = 0; ks < 4; ++ks) {
            const unsigned* yp = ypk + yrow + ks * 16 + half * 8;
            unpack8(*(const uint4*)yp, *(const uint4*)(yp + 4), qhf[ks], qlf[ks]);
        }
    }

    // stage w slice to LDS
    for (int i = tid; i < GHALF; i += 256) wssh[i] = wv[bq + gstart + i];

    // staging geometry: LDS row = g-row (256B) = [hi 8 chunks][lo 8],
    // chunk slot c ^ (row&15). Each wave stages 2KB = 2 x 16B per lane.
    const int D0 = (wid * 2) * 1024 + lane * 16;
    const int D1 = D0 + 1024;
    const int row0 = D0 >> 8, row1 = D1 >> 8;
    const int c0 = ((D0 >> 4) & 15) ^ (row0 & 15);
    const int c1 = ((D1 >> 4) & 15) ^ (row1 & 15);
    const unsigned short* sb0 = (c0 < 8) ? xh : xl;
    const unsigned short* sb1 = (c1 < 8) ? xh : xl;
    const int so0 = (c0 & 7) * 8, so1 = (c1 & 7) * 8;

    float lsum = 0.f, asum = 0.f;

    uint4 st0 = *(const uint4*)(sb0 + (bq + gstart + row0) * DPAD + so0);
    uint4 st1 = *(const uint4*)(sb1 + (bq + gstart + row1) * DPAD + so1);

    const int rbase = col << 8;
    const int r15 = col & 15;

    for (int t = 0; t < NSTEP; ++t) {
        const int buf = t & 1;

        *(uint4*)(&Kt[buf][D0]) = st0;
        *(uint4*)(&Kt[buf][D1]) = st1;
        if (t + 1 < NSTEP) {
            const int gn = gstart + (t + 1) * GSTEP;
            st0 = *(const uint4*)(sb0 + (bq + gn + row0) * DPAD + so0);
            st1 = *(const uint4*)(sb1 + (bq + gn + row1) * DPAD + so1);
        }
        __syncthreads();

        f32x16 acc;
        #pragma unroll
        for (int i = 0; i < 16; ++i) acc[i] = 0.f;

        #pragma unroll
        for (int ks = 0; ks < 4; ++ks) {
            const int ch = ks * 2 + half;
            bf16x8 ahf = *(const bf16x8*)(&Kt[buf][rbase + ((ch ^ r15) << 4)]);
            bf16x8 alf = *(const bf16x8*)(&Kt[buf][rbase + (((8 + ch) ^ r15) << 4)]);
            acc = __builtin_amdgcn_mfma_f32_32x32x16_bf16(ahf, qlf[ks], acc, 0, 0, 0);
            acc = __builtin_amdgcn_mfma_f32_32x32x16_bf16(alf, qhf[ks], acc, 0, 0, 0);
            acc = __builtin_amdgcn_mfma_f32_32x32x16_bf16(ahf, qhf[ks], acc, 0, 0, 0);
        }

        // softmax accumulation; D row g = (reg&3) + 8*(reg>>2) + 4*half
        const float* wp = wssh + t * GSTEP + 4 * half;
        #pragma unroll
        for (int q = 0; q < 4; ++q) {
            float4 w4 = *(const float4*)(wp + q * 8);
            float p0 = __expf(acc[q * 4 + 0]);
            float p1 = __expf(acc[q * 4 + 1]);
            float p2 = __expf(acc[q * 4 + 2]);
            float p3 = __expf(acc[q * 4 + 3]);
            lsum += ((p0 + p1) + (p2 + p3));
            asum = fmaf(p0, w4.x, fmaf(p1, w4.y, fmaf(p2, w4.z, fmaf(p3, w4.w, asum))));
        }
    }

    lsum += __shfl_xor(lsum, 32);
    asum += __shfl_xor(asum, 32);
    if (half == 0) {
        size_t o = ((size_t)sp * BB + b) * FF + fbase + col;
        partL[o] = lsum;
        partA[o] = asum;
    }
}

// ---------------------------------------------------------------------------
// bn: combine split partials, BatchNorm over batch per channel f.
// ---------------------------------------------------------------------------
__global__ __launch_bounds__(256) void bn_kernel(
    const float* __restrict__ partL, const float* __restrict__ partA,
    const float* __restrict__ gamma, const float* __restrict__ beta,
    float* __restrict__ out)
{
    const int f = blockIdx.x * 256 + threadIdx.x;
    float v[BB];
    float mean = 0.f;
    #pragma unroll
    for (int b = 0; b < BB; ++b) {
        float l = 0.f, a = 0.f;
        #pragma unroll
        for (int s = 0; s < SPLIT; ++s) {
            l += partL[((size_t)s * BB + b) * FF + f];
            a += partA[((size_t)s * BB + b) * FF + f];
        }
        v[b] = a / l;
        mean += v[b];
    }
    mean *= (1.f / BB);
    float var = 0.f;
    #pragma unroll
    for (int b = 0; b < BB; ++b) {
        float d = v[b] - mean;
        var = fmaf(d, d, var);
    }
    var *= (1.f / BB);
    const float inv = rsqrtf(var + 1e-5f);
    const float g = gamma[f], be = beta[f];
    #pragma unroll
    for (int b = 0; b < BB; ++b)
        out[((size_t)b << 11) + f] = (v[b] - mean) * inv * g + be;
}

// ---------------------------------------------------------------------------
extern "C" void kernel_launch(void* const* d_in, const int* in_sizes, int n_in,
                              void* d_out, int out_size, void* d_ws, size_t ws_size,
                              hipStream_t stream)
{
    const float* x     = (const float*)d_in[0];
    const float* Wqkv  = (const float*)d_in[1];
    const float* Wout  = (const float*)d_in[2];
    // d_in[3] = b_out: cancels exactly under BatchNorm mean subtraction.
    const float* gamma = (const float*)d_in[4];
    const float* beta  = (const float*)d_in[5];

    char* wsb = (char*)d_ws;
    const size_t PANEL = (size_t)ROWS * DPAD * sizeof(unsigned short);  // 8 MB
    unsigned short* xh = (unsigned short*)(wsb);
    unsigned short* xl = (unsigned short*)(wsb + PANEL);
    unsigned*      ypk = (unsigned*)(wsb + 2 * PANEL);                  // 16 MB
    float*          wv = (float*)(wsb + 4 * PANEL);                     // 256 KB
    unsigned*     Mtpk = (unsigned*)(wsb + 4 * PANEL + 262144);         // 16 KB
    float*           u = (float*)(wsb + 4 * PANEL + 262144 + 16384);    // 1 KB pad
    float*       partL = (float*)(wsb + 4 * PANEL + 262144 + 17408);
    float*       partA = partL + (size_t)SPLIT * BB * FF;
    // total ~= 34.3 MiB

    prep_kernel<<<dim3(17), dim3(256), 0, stream>>>(Wqkv, Wout, Mtpk, u);

    xconv_kernel<<<dim3(ROWS / 64), dim3(256), 0, stream>>>(x, u, xh, xl, wv);

    ymm_kernel<<<dim3(ROWS / 128), dim3(256), 0, stream>>>(xh, xl, Mtpk, ypk);

    attn_kernel<<<dim3(BB * (FF / FBLK) * SPLIT), dim3(256), 0, stream>>>(
        xh, xl, ypk, wv, partL, partA);

    bn_kernel<<<dim3(FF / 256), dim3(256), 0, stream>>>(
        partL, partA, gamma, beta, (float*)d_out);
}